// Round 4
// baseline (6877.137 us; speedup 1.0000x reference)
//
#include <hip/hip_runtime.h>
#include <hip/hip_bf16.h>
#include <cmath>

#define DEV __device__ __forceinline__

namespace {

constexpr int kB = 8, kN = 4096, kD = 512, kH = 8, kDH = 64, kM = 256, kL = 16, kCK = 33;
constexpr int kBN = kB * kN;     // 32768
constexpr int kBH = kB * kH;     // 64
constexpr int kHD = kH * kDH;    // 512
constexpr int kD4 = 4 * kD;      // 2048
constexpr int kQKVC = 3 * kHD;   // 1536

DEV float toF(float x) { return x; }
DEV float toF(__hip_bfloat16 x) { return __bfloat162float(x); }
DEV __hip_bfloat16 f2b(float f) { return __float2bfloat16(f); }
DEV float us2f(unsigned short u) { return __uint_as_float((unsigned)u << 16); }
DEV unsigned short f2us(float f) {
  __hip_bfloat16 h = __float2bfloat16(f);
  return *reinterpret_cast<unsigned short*>(&h);
}
DEV float lo16(unsigned u) { return __uint_as_float(u << 16); }
DEV float hi16(unsigned u) { return __uint_as_float(u & 0xffff0000u); }

DEV float waveSum(float v) {
#pragma unroll
  for (int o = 32; o > 0; o >>= 1) v += __shfl_down(v, o, 64);
  return v;
}
DEV float waveMax(float v) {
#pragma unroll
  for (int o = 32; o > 0; o >>= 1) v = fmaxf(v, __shfl_down(v, o, 64));
  return v;
}
DEV float blockSum(float v, float* sb) {
  v = waveSum(v);
  int lane = threadIdx.x & 63, w = threadIdx.x >> 6;
  __syncthreads();
  if (lane == 0) sb[w] = v;
  __syncthreads();
  return sb[0] + sb[1] + sb[2] + sb[3];
}
DEV float blockMax(float v, float* sb) {
  v = waveMax(v);
  int lane = threadIdx.x & 63, w = threadIdx.x >> 6;
  __syncthreads();
  if (lane == 0) sb[w] = v;
  __syncthreads();
  return fmaxf(fmaxf(sb[0], sb[1]), fmaxf(sb[2], sb[3]));
}

// ---------------- runtime dtype detection ----------------
// Samples 4096 32-bit words of X. For true-bf16 data, ~100% of 16-bit halves
// decode to sane magnitudes; for f32 data misread as bf16, the mantissa halves
// have a uniform-random exponent field -> only ~64% look sane. Threshold 90%.
__global__ __launch_bounds__(256) void detect_k(const unsigned* __restrict__ x,
                                                int* __restrict__ flag) {
  __shared__ int sc[4];
  int t = threadIdx.x;
  int cb = 0;
  for (int i = t; i < 4096; i += 256) {
    unsigned w = x[i];
    float b0 = __uint_as_float(w << 16);
    float b1 = __uint_as_float(w & 0xffff0000u);
    if (fabsf(b0) < 64.0f && (b0 == 0.0f || fabsf(b0) > 1e-20f)) cb++;
    if (fabsf(b1) < 64.0f && (b1 == 0.0f || fabsf(b1) > 1e-20f)) cb++;
  }
#pragma unroll
  for (int o = 32; o > 0; o >>= 1) cb += __shfl_down(cb, o, 64);
  if ((t & 63) == 0) sc[t >> 6] = cb;
  __syncthreads();
  if (t == 0) flag[0] = (sc[0] + sc[1] + sc[2] + sc[3] > 7373) ? 1 : 0;  // 1 = bf16 inputs
}

// flag-aware input -> f32 conversion
__global__ void cvt_any_k(const void* __restrict__ s, float* __restrict__ d, int n,
                          const int* __restrict__ flag) {
  int i = blockIdx.x * 256 + threadIdx.x;
  if (i >= n) return;
  if (*flag)
    d[i] = toF(((const __hip_bfloat16*)s)[i]);
  else
    d[i] = ((const float*)s)[i];
}

// ---------------- LN kernels ----------------

__global__ __launch_bounds__(256) void ln1_k(const void* __restrict__ xv,
                                             const float* __restrict__ g,
                                             const float* __restrict__ be,
                                             __hip_bfloat16* __restrict__ o,
                                             const int* __restrict__ flag) {
  __shared__ float sb[4];
  size_t row = blockIdx.x;
  __hip_bfloat16* po = o + row * kD;
  int t = threadIdx.x;
  float v0, v1;
  if (*flag) {
    const __hip_bfloat16* pr = (const __hip_bfloat16*)xv + row * kD;
    v0 = toF(pr[t]);
    v1 = toF(pr[t + 256]);
  } else {
    const float* pr = (const float*)xv + row * kD;
    v0 = pr[t];
    v1 = pr[t + 256];
  }
  float s = blockSum(v0 + v1, sb);
  float ss = blockSum(v0 * v0 + v1 * v1, sb);
  float mu = s * (1.0f / kD);
  float var = ss * (1.0f / kD) - mu * mu;
  float rs = rsqrtf(var + 1e-5f);
  po[t] = f2b((v0 - mu) * rs * g[t] + be[t]);
  po[t + 256] = f2b((v1 - mu) * rs * g[t + 256] + be[t + 256]);
}

__global__ __launch_bounds__(256) void ln2stats_k(const float* __restrict__ x,
                                                  float* __restrict__ st) {
  __shared__ float sb[4];
  size_t row = blockIdx.x;
  const float* pr = x + row * kD;
  int t = threadIdx.x;
  float v0 = pr[t], v1 = pr[t + 256];
  float s = blockSum(v0 + v1, sb);
  float ss = blockSum(v0 * v0 + v1 * v1, sb);
  if (t == 0) {
    float mu = s * (1.0f / kD);
    float var = ss * (1.0f / kD) - mu * mu;
    st[2 * row] = mu;
    st[2 * row + 1] = rsqrtf(var + 1e-5f);
  }
}

// ---------------- small helpers ----------------

__global__ void landmark_k(const __hip_bfloat16* __restrict__ src, float* __restrict__ dst) {
  int i = blockIdx.x * 256 + threadIdx.x;  // (bh,m,dh) = 2^20
  if (i >= kBH * kM * kDH) return;
  int dh = i & 63, m = (i >> 6) & 255, bh = i >> 14;
  const __hip_bfloat16* p = src + ((size_t)bh * kN + m * kL) * kDH + dh;
  float s = 0.f;
#pragma unroll
  for (int l = 0; l < kL; ++l) s += toF(p[l * kDH]);
  dst[i] = s * (1.0f / kL);
}

__global__ __launch_bounds__(256) void softmax_k(float* __restrict__ X, int ncols) {
  __shared__ float sb[4];
  size_t row = blockIdx.x;
  float* p = X + row * ncols;
  int t = threadIdx.x;
  float mx = -1e30f;
  for (int c = t; c < ncols; c += 256) mx = fmaxf(mx, p[c]);
  mx = blockMax(mx, sb);
  float s = 0.f;
  for (int c = t; c < ncols; c += 256) {
    float e = expf(fminf(p[c] - mx, 0.0f));
    p[c] = e;
    s += e;
  }
  s = blockSum(s, sb);
  float inv = 1.0f / s;
  for (int c = t; c < ncols; c += 256) p[c] *= inv;
}

__global__ __launch_bounds__(256) void pinv_rowcol_k(const float* __restrict__ a2,
                                                     float* __restrict__ rsum,
                                                     float* __restrict__ csum) {
  __shared__ float sb[4];
  int bh = blockIdx.x >> 8, i = blockIdx.x & 255;
  const float* base = a2 + ((size_t)bh << 16);
  int t = threadIdx.x;
  float rs = blockSum(fabsf(base[i * kM + t]), sb);
  float cs = blockSum(fabsf(base[t * kM + i]), sb);
  if (t == 0) {
    rsum[blockIdx.x] = rs;
    csum[blockIdx.x] = cs;
  }
}

__global__ __launch_bounds__(256) void pinv_gmax_k(const float* __restrict__ rsum,
                                                   const float* __restrict__ csum,
                                                   float* __restrict__ gmax) {
  __shared__ float sb[4];
  int t = threadIdx.x;
  float a = 0.f, b = 0.f;
  for (int j = t; j < kBH * kM; j += 256) {
    a = fmaxf(a, rsum[j]);
    b = fmaxf(b, csum[j]);
  }
  a = blockMax(a, sb);
  b = blockMax(b, sb);
  if (t == 0) {
    gmax[0] = a;
    gmax[1] = b;
  }
}

__global__ void pinv_init_k(const float* __restrict__ a2, const float* __restrict__ gmax,
                            float* __restrict__ z) {
  int i = blockIdx.x * 256 + threadIdx.x;  // 2^22
  if (i >= kBH * kM * kM) return;
  int col = i & 255, r = (i >> 8) & 255, bh = i >> 16;
  float denom = fmaxf(gmax[0] * gmax[1], 1e-30f);
  z[i] = a2[((size_t)bh << 16) + col * kM + r] / denom;
}

__global__ void eye_sub_k(float* __restrict__ dst, const float* __restrict__ src, float c,
                          float scale) {
  int i = blockIdx.x * 256 + threadIdx.x;
  if (i >= kBH * kM * kM) return;
  int col = i & 255, r = (i >> 8) & 255;
  dst[i] = (((r == col) ? c : 0.0f) - src[i]) * scale;
}

// conv residual, added into merged-layout bf16 attn output
__global__ void conv_add_k(const __hip_bfloat16* __restrict__ v, const float* __restrict__ w,
                           __hip_bfloat16* __restrict__ ao) {
  int i = blockIdx.x * 256 + threadIdx.x;  // merged (b,n,h,dh)
  if (i >= kBN * kHD) return;
  int dh = i & 63, h = (i >> 6) & 7, n = (i >> 9) & (kN - 1), b = i >> 21;
  const __hip_bfloat16* vp = v + ((size_t)(b * kH + h) * kN) * kDH + dh;
  float s = 0.f;
#pragma unroll
  for (int kk = 0; kk < kCK; ++kk) {
    int nn = n + kk - kCK / 2;
    if (nn >= 0 && nn < kN) s += toF(vp[(size_t)nn * kDH]) * w[h * kCK + kk];
  }
  ao[i] = f2b(toF(ao[i]) + s);
}

// ---------------- fused streaming attention kernels ----------------

// w3[bh,m,:] = softmax(q_l[bh,m,:] @ k^T) @ v ; 4 m-rows per block
__global__ __launch_bounds__(256) void attn3v_k(const float* __restrict__ ql,
                                                const __hip_bfloat16* __restrict__ k,
                                                const __hip_bfloat16* __restrict__ v,
                                                float* __restrict__ w3) {
  __shared__ float qrow[4][64];
  __shared__ unsigned short p[4][4096];  // exp(scores) bf16
  __shared__ float red[4][4][64];
  __shared__ float sb[4];
  int bh = blockIdx.x >> 6, m0 = (blockIdx.x & 63) * 4;
  int t = threadIdx.x;
  {
    int m4 = t >> 6, d = t & 63;
    qrow[m4][d] = ql[((size_t)bh * kM + m0 + m4) * kDH + d];
  }
  __syncthreads();
  const __hip_bfloat16* kp = k + (size_t)bh * kN * kDH;
  float s[4][16];
  float lmax[4] = {-1e30f, -1e30f, -1e30f, -1e30f};
  for (int c = 0; c < 16; ++c) {
    int n = c * 256 + t;
    const uint4* kr = reinterpret_cast<const uint4*>(kp + (size_t)n * kDH);
    float sm[4] = {0.f, 0.f, 0.f, 0.f};
#pragma unroll
    for (int g = 0; g < 8; ++g) {
      uint4 u = kr[g];
      float f[8] = {lo16(u.x), hi16(u.x), lo16(u.y), hi16(u.y),
                    lo16(u.z), hi16(u.z), lo16(u.w), hi16(u.w)};
#pragma unroll
      for (int e = 0; e < 8; ++e) {
        float kv = f[e];
#pragma unroll
        for (int m = 0; m < 4; ++m) sm[m] += kv * qrow[m][g * 8 + e];
      }
    }
#pragma unroll
    for (int m = 0; m < 4; ++m) {
      s[m][c] = sm[m];
      lmax[m] = fmaxf(lmax[m], sm[m]);
    }
  }
  float mx[4];
#pragma unroll
  for (int m = 0; m < 4; ++m) mx[m] = blockMax(lmax[m], sb);
  float lsum[4] = {0.f, 0.f, 0.f, 0.f};
  for (int c = 0; c < 16; ++c) {
    int n = c * 256 + t;
#pragma unroll
    for (int m = 0; m < 4; ++m) {
      float e = expf(fminf(s[m][c] - mx[m], 0.0f));
      p[m][n] = f2us(e);
      lsum[m] += e;
    }
  }
  float inv[4];
#pragma unroll
  for (int m = 0; m < 4; ++m) inv[m] = 1.0f / blockSum(lsum[m], sb);
  __syncthreads();
  // phase 2: P @ V
  int chunk = t >> 6, dh = t & 63;
  float acc[4] = {0.f, 0.f, 0.f, 0.f};
  const __hip_bfloat16* vb = v + ((size_t)bh * kN + chunk * 1024) * kDH + dh;
  for (int ni = 0; ni < 1024; ++ni) {
    float pv = toF(vb[(size_t)ni * kDH]);
    int n = chunk * 1024 + ni;
#pragma unroll
    for (int m = 0; m < 4; ++m) acc[m] += us2f(p[m][n]) * pv;
  }
#pragma unroll
  for (int m = 0; m < 4; ++m) red[chunk][m][dh] = acc[m];
  __syncthreads();
  {
    int m = t >> 6, d2 = t & 63;
    float s2 = red[0][m][d2] + red[1][m][d2] + red[2][m][d2] + red[3][m][d2];
    w3[((size_t)bh * kM + m0 + m) * kDH + d2] = s2 * inv[m];
  }
}

// ao[b,n0+r, h*64+dh] = softmax(q[bh,n,:] @ k_l^T) @ y ; 64 n-rows per block
__global__ __launch_bounds__(256) void attn1y_k(const __hip_bfloat16* __restrict__ q,
                                                const float* __restrict__ kl,
                                                const float* __restrict__ y,
                                                __hip_bfloat16* __restrict__ ao) {
  __shared__ float qt[64][64];
  __shared__ unsigned short p[64][256];
  __shared__ float m4[64][4];
  __shared__ float rinv[64];
  int bh = blockIdx.x >> 6, n0 = (blockIdx.x & 63) * 64;
  int b = bh >> 3, h = bh & 7;
  int t = threadIdx.x;
  const __hip_bfloat16* qp = q + ((size_t)bh * kN + n0) * kDH;
#pragma unroll
  for (int i = 0; i < 16; ++i) {
    int idx = t + i * 256;
    int r = idx >> 6, d = idx & 63;
    qt[r][d] = toF(qp[(size_t)r * kDH + d]);
  }
  __syncthreads();
  float klr[64];
  const float* klp = kl + ((size_t)bh * kM + t) * kDH;
#pragma unroll
  for (int d = 0; d < 64; ++d) klr[d] = klp[d];
  for (int r = 0; r < 64; ++r) {
    float s = 0.f;
#pragma unroll
    for (int d = 0; d < 64; ++d) s += qt[r][d] * klr[d];
    p[r][t] = f2us(s);
  }
  __syncthreads();
  int r = t >> 2, seg = t & 3;
  float mx = -1e30f;
  for (int j = seg * 64; j < seg * 64 + 64; ++j) mx = fmaxf(mx, us2f(p[r][j]));
  m4[r][seg] = mx;
  __syncthreads();
  float rm = fmaxf(fmaxf(m4[r][0], m4[r][1]), fmaxf(m4[r][2], m4[r][3]));
  __syncthreads();
  float sum = 0.f;
  for (int j = seg * 64; j < seg * 64 + 64; ++j) {
    float e = expf(fminf(us2f(p[r][j]) - rm, 0.0f));
    p[r][j] = f2us(e);
    sum += e;
  }
  m4[r][seg] = sum;
  __syncthreads();
  if (seg == 0) rinv[r] = 1.0f / (m4[r][0] + m4[r][1] + m4[r][2] + m4[r][3]);
  __syncthreads();
  int dh = t & 63, rg = t >> 6;
  const float* yp = y + (size_t)bh * kM * kDH + dh;
  for (int rr = rg * 16; rr < rg * 16 + 16; ++rr) {
    float acc = 0.f;
    for (int j = 0; j < 256; ++j) acc += us2f(p[rr][j]) * yp[(size_t)j * kDH];
    acc *= rinv[rr];
    ao[((size_t)(b * kN + n0 + rr)) * kHD + h * kDH + dh] = f2b(acc);
  }
}

// ---------------- generic tiled GEMM (fp32 accumulate) ----------------
constexpr int EPI_F32 = 0, EPI_QKV = 1, EPI_BIAS_F32 = 2, EPI_GELU_BF16 = 3, EPI_RES_OUT = 4;

struct EpiArgs {
  const float* bias;
  const float* res;
  __hip_bfloat16* oq;
  __hip_bfloat16* ok;
  __hip_bfloat16* ov;
  __hip_bfloat16* obf;
  const float* stats;
  const float* g;
  const float* be;
  void* ovoid;
  const int* flag;
};

template <int EPI, bool TRB, bool LNA, class TAT, class TBT>
__global__ __launch_bounds__(256) void gemm_k(const TAT* __restrict__ A, int lda, long sA,
                                              const TBT* __restrict__ B, int ldb, long sB,
                                              float* __restrict__ C, int ldc, long sC, int K,
                                              EpiArgs ep) {
  __shared__ float As[16][68];
  __shared__ float Bs[16][68];
  A += (long)blockIdx.z * sA;
  B += (long)blockIdx.z * sB;
  const long cbase = (long)blockIdx.z * sC;
  const int row0 = blockIdx.x * 64, col0 = blockIdx.y * 64;
  const int t = threadIdx.x;
  const int ty = t >> 4, tx = t & 15;
  float acc[4][4] = {{0.f, 0.f, 0.f, 0.f}, {0.f, 0.f, 0.f, 0.f},
                     {0.f, 0.f, 0.f, 0.f}, {0.f, 0.f, 0.f, 0.f}};
  const int ka = t & 15, ra = t >> 4;
  for (int k0 = 0; k0 < K; k0 += 16) {
#pragma unroll
    for (int j = 0; j < 4; ++j) {
      int r = row0 + ra + 16 * j;
      float v = toF(A[(long)r * lda + (k0 + ka)]);
      if (LNA) {
        v = (v - ep.stats[2 * r]) * ep.stats[2 * r + 1] * ep.g[k0 + ka] + ep.be[k0 + ka];
      }
      As[ka][ra + 16 * j] = v;
    }
    if (TRB) {
#pragma unroll
      for (int j = 0; j < 4; ++j)
        Bs[ka][ra + 16 * j] = toF(B[(long)(col0 + ra + 16 * j) * ldb + (k0 + ka)]);
    } else {
      const int jb = t & 63, kb = t >> 6;
#pragma unroll
      for (int j = 0; j < 4; ++j)
        Bs[kb + 4 * j][jb] = toF(B[(long)(k0 + kb + 4 * j) * ldb + (col0 + jb)]);
    }
    __syncthreads();
#pragma unroll
    for (int kk = 0; kk < 16; ++kk) {
      float av[4], bv[4];
#pragma unroll
      for (int i = 0; i < 4; ++i) av[i] = As[kk][ty * 4 + i];
#pragma unroll
      for (int j = 0; j < 4; ++j) bv[j] = Bs[kk][tx * 4 + j];
#pragma unroll
      for (int i = 0; i < 4; ++i)
#pragma unroll
        for (int j = 0; j < 4; ++j) acc[i][j] += av[i] * bv[j];
    }
    __syncthreads();
  }
#pragma unroll
  for (int i = 0; i < 4; ++i) {
    int r = row0 + ty * 4 + i;
#pragma unroll
    for (int j = 0; j < 4; ++j) {
      int c = col0 + tx * 4 + j;
      float v = acc[i][j];
      if (EPI == EPI_F32) {
        C[cbase + (long)r * ldc + c] = v;
      } else if (EPI == EPI_QKV) {
        int three = c >> 9, h = (c >> 6) & 7, dh = c & 63;
        int b = r >> 12, n = r & (kN - 1);
        long dst = ((long)(b * kH + h) * kN + n) * kDH + dh;
        if (three == 0)
          ep.oq[dst] = f2b(v * 0.125f);
        else if (three == 1)
          ep.ok[dst] = f2b(v);
        else
          ep.ov[dst] = f2b(v);
      } else if (EPI == EPI_BIAS_F32) {
        C[cbase + (long)r * ldc + c] = v + ep.bias[c];
      } else if (EPI == EPI_GELU_BF16) {
        v += ep.bias[c];
        ep.obf[cbase + (long)r * ldc + c] = f2b(0.5f * v * (1.0f + erff(v * 0.70710678118654752f)));
      } else {  // EPI_RES_OUT: +bias+residual, dtype-flagged final store (NaN-scrubbed)
        long idx = cbase + (long)r * ldc + c;
        float v2 = v + ep.bias[c] + ep.res[idx];
        if (!(v2 == v2)) v2 = 0.0f;
        if (*ep.flag)
          ((__hip_bfloat16*)ep.ovoid)[idx] = f2b(v2);
        else
          ((float*)ep.ovoid)[idx] = v2;
      }
    }
  }
}

}  // namespace

extern "C" void kernel_launch(void* const* d_in, const int* in_sizes, int n_in, void* d_out,
                              int out_size, void* d_ws, size_t ws_size, hipStream_t stream) {
  (void)in_sizes; (void)n_in; (void)out_size;

  char* base = (char*)d_ws;
  size_t off = 0;
  auto alloc = [&](size_t bytes) {
    char* p = base + off;
    off = (off + bytes + 255) & ~(size_t)255;
    return p;
  };
  // pinv pool (also hosts hln early, hbuf late)
  float* a2 = (float*)alloc((size_t)kBH * kM * kM * 4);  // 16.78 MB each
  float* pz = (float*)alloc((size_t)kBH * kM * kM * 4);
  float* px = (float*)alloc((size_t)kBH * kM * kM * 4);
  float* pe = (float*)alloc((size_t)kBH * kM * kM * 4);
  float* pf = (float*)alloc((size_t)kBH * kM * kM * 4);
  // bf16 qkv + attn-out region (also hosts MLP hidden late)
  __hip_bfloat16* q = (__hip_bfloat16*)alloc((size_t)kBH * kN * kDH * 2);  // 33.55 MB each
  __hip_bfloat16* kk = (__hip_bfloat16*)alloc((size_t)kBH * kN * kDH * 2);
  __hip_bfloat16* vv = (__hip_bfloat16*)alloc((size_t)kBH * kN * kDH * 2);
  __hip_bfloat16* ao = (__hip_bfloat16*)alloc((size_t)kBN * kHD * 2);
  float* ql = (float*)alloc((size_t)kBH * kM * kDH * 4);  // 4.19 MB each
  float* kl = (float*)alloc((size_t)kBH * kM * kDH * 4);
  float* w3 = (float*)alloc((size_t)kBH * kM * kDH * 4);
  float* y = (float*)alloc((size_t)kBH * kM * kDH * 4);
  float* st2 = (float*)alloc((size_t)kBN * 2 * 4);
  float* rsum = (float*)alloc((size_t)kBH * kM * 4);
  float* csum = (float*)alloc((size_t)kBH * kM * 4);
  float* gmax = (float*)alloc(256);
  int* dflag = (int*)alloc(256);
  // converted f32 weights (~12.6 MB)
  float* wqkv_f = (float*)alloc((size_t)kD * kQKVC * 4);
  float* wout_f = (float*)alloc((size_t)kHD * kD * 4);
  float* w1_f = (float*)alloc((size_t)kD * kD4 * 4);
  float* w2_f = (float*)alloc((size_t)kD4 * kD * 4);
  float* bout_f = (float*)alloc(kD * 4);
  float* b1_f = (float*)alloc(kD4 * 4);
  float* b2_f = (float*)alloc(kD * 4);
  float* convw_f = (float*)alloc(kH * kCK * 4);
  float* g1_f = (float*)alloc(kD * 4);
  float* be1_f = (float*)alloc(kD * 4);
  float* g2_f = (float*)alloc(kD * 4);
  float* be2_f = (float*)alloc(kD * 4);
  // lifetime-disjoint aliases
  __hip_bfloat16* hln = (__hip_bfloat16*)a2;  // LN1 out (spans a2+pz, both dead then)
  float* hbuf = a2;                           // Wout out (spans a2..pe, pinv dead then)
  __hip_bfloat16* hidden = q;                 // MLP hidden (spans q..ao, all dead then)

  if (off > ws_size) return;  // deterministic guard

  // dtype detection from X
  detect_k<<<1, 256, 0, stream>>>((const unsigned*)d_in[0], dflag);

  auto cvt = [&](const void* src, float* dst, int n) {
    cvt_any_k<<<(n + 255) / 256, 256, 0, stream>>>(src, dst, n, dflag);
  };
  cvt(d_in[1], wqkv_f, kD * kQKVC);
  cvt(d_in[2], wout_f, kHD * kD);
  cvt(d_in[3], bout_f, kD);
  cvt(d_in[4], convw_f, kH * kCK);
  cvt(d_in[5], g1_f, kD);
  cvt(d_in[6], be1_f, kD);
  cvt(d_in[7], g2_f, kD);
  cvt(d_in[8], be2_f, kD);
  cvt(d_in[9], w1_f, kD * kD4);
  cvt(d_in[10], b1_f, kD4);
  cvt(d_in[11], w2_f, kD4 * kD);
  cvt(d_in[12], b2_f, kD);

  EpiArgs e0 = {};

  // LN1 -> hln (bf16)
  ln1_k<<<kBN, 256, 0, stream>>>(d_in[0], g1_f, be1_f, hln, dflag);

  // QKV GEMM with scatter epilogue -> q,k,v (bf16), q pre-scaled by DH^-0.5
  EpiArgs eq = {};
  eq.oq = q; eq.ok = kk; eq.ov = vv;
  gemm_k<EPI_QKV, false, false, __hip_bfloat16, float>
      <<<dim3(kBN / 64, kQKVC / 64, 1), 256, 0, stream>>>(hln, kD, 0, wqkv_f, kQKVC, 0, nullptr,
                                                          0, 0, kD, eq);

  // landmarks (f32)
  landmark_k<<<(kBH * kM * kDH + 255) / 256, 256, 0, stream>>>(q, ql);
  landmark_k<<<(kBH * kM * kDH + 255) / 256, 256, 0, stream>>>(kk, kl);

  const long sQL = (long)kM * kDH, sA2 = (long)kM * kM;

  // sim2 = q_l @ k_l^T -> a2 ; softmax
  gemm_k<EPI_F32, true, false, float, float><<<dim3(kM / 64, kM / 64, kBH), 256, 0, stream>>>(
      ql, kDH, sQL, kl, kDH, sQL, a2, kM, sA2, kDH, e0);
  softmax_k<<<kBH * kM, 256, 0, stream>>>(a2, kM);

  // pinv init (deterministic two-stage max)
  pinv_rowcol_k<<<kBH * kM, 256, 0, stream>>>(a2, rsum, csum);
  pinv_gmax_k<<<1, 256, 0, stream>>>(rsum, csum, gmax);
  pinv_init_k<<<(kBH * kM * kM + 255) / 256, 256, 0, stream>>>(a2, gmax, pz);

  // Newton-Schulz (f32 batched GEMMs)
  dim3 gP(kM / 64, kM / 64, kBH);
  int nEye = (kBH * kM * kM + 255) / 256;
  float* zc = pz;
  float* zx = px;
  for (int it = 0; it < 6; ++it) {
    gemm_k<EPI_F32, false, false, float, float><<<gP, 256, 0, stream>>>(a2, kM, sA2, zc, kM, sA2,
                                                                        zx, kM, sA2, kM, e0);
    eye_sub_k<<<nEye, 256, 0, stream>>>(pe, zx, 7.0f, 1.0f);
    gemm_k<EPI_F32, false, false, float, float><<<gP, 256, 0, stream>>>(zx, kM, sA2, pe, kM, sA2,
                                                                        pf, kM, sA2, kM, e0);
    eye_sub_k<<<nEye, 256, 0, stream>>>(pf, pf, 15.0f, 1.0f);
    gemm_k<EPI_F32, false, false, float, float><<<gP, 256, 0, stream>>>(zx, kM, sA2, pf, kM, sA2,
                                                                        pe, kM, sA2, kM, e0);
    eye_sub_k<<<nEye, 256, 0, stream>>>(pe, pe, 13.0f, 0.25f);
    gemm_k<EPI_F32, false, false, float, float><<<gP, 256, 0, stream>>>(zc, kM, sA2, pe, kM, sA2,
                                                                        zx, kM, sA2, kM, e0);
    float* tmp = zc; zc = zx; zx = tmp;
  }

  // w3 = softmax(q_l @ k^T) @ v   (fused, streaming)
  attn3v_k<<<kBH * (kM / 4), 256, 0, stream>>>(ql, kk, vv, w3);

  // y = z @ w3
  gemm_k<EPI_F32, false, false, float, float><<<dim3(kM / 64, 1, kBH), 256, 0, stream>>>(
      zc, kM, sA2, w3, kDH, sQL, y, kDH, sQL, kM, e0);

  // ao = softmax(q @ k_l^T) @ y  (fused, merged (b,n,h*dh) bf16)
  attn1y_k<<<kBH * (kN / 64), 256, 0, stream>>>(q, kl, y, ao);

  // + depthwise conv residual on v
  conv_add_k<<<(kBN * kHD + 255) / 256, 256, 0, stream>>>(vv, convw_f, ao);

  // hbuf = ao @ Wout + bout (f32)
  EpiArgs ew = {};
  ew.bias = bout_f;
  gemm_k<EPI_BIAS_F32, false, false, __hip_bfloat16, float>
      <<<dim3(kBN / 64, kD / 64, 1), 256, 0, stream>>>(ao, kHD, 0, wout_f, kD, 0, hbuf, kD, 0,
                                                       kHD, ew);

  // LN2 stats, MLP1 (LN fused into A-load, +bias+GELU -> bf16 hidden)
  ln2stats_k<<<kBN, 256, 0, stream>>>(hbuf, st2);
  EpiArgs e1 = {};
  e1.bias = b1_f; e1.stats = st2; e1.g = g2_f; e1.be = be2_f; e1.obf = hidden;
  gemm_k<EPI_GELU_BF16, false, true, float, float>
      <<<dim3(kBN / 64, kD4 / 64, 1), 256, 0, stream>>>(hbuf, kD, 0, w1_f, kD4, 0, nullptr, kD4,
                                                        0, kD, e1);

  // MLP2 (+bias+residual -> flag-typed out)
  EpiArgs e2 = {};
  e2.bias = b2_f; e2.res = hbuf; e2.ovoid = d_out; e2.flag = dflag;
  gemm_k<EPI_RES_OUT, false, false, __hip_bfloat16, float>
      <<<dim3(kBN / 64, kD / 64, 1), 256, 0, stream>>>(hidden, kD4, 0, w2_f, kD, 0, nullptr, kD,
                                                       0, kD4, e2);
}

// Round 5
// 3724.927 us; speedup vs baseline: 1.8462x; 1.8462x over previous
//
#include <hip/hip_runtime.h>
#include <hip/hip_bf16.h>
#include <cmath>

#define DEV __device__ __forceinline__

namespace {

constexpr int kB = 8, kN = 4096, kD = 512, kH = 8, kDH = 64, kM = 256, kL = 16, kCK = 33;
constexpr int kBN = kB * kN;     // 32768
constexpr int kBH = kB * kH;     // 64
constexpr int kHD = kH * kDH;    // 512
constexpr int kD4 = 4 * kD;      // 2048
constexpr int kQKVC = 3 * kHD;   // 1536

typedef __attribute__((ext_vector_type(8))) short short8;
typedef __attribute__((ext_vector_type(4))) float f32x4;

DEV float toF(float x) { return x; }
DEV float toF(__hip_bfloat16 x) { return __bfloat162float(x); }
DEV __hip_bfloat16 f2b(float f) { return __float2bfloat16(f); }
DEV short f2s(float f) {
  __hip_bfloat16 h = __float2bfloat16(f);
  return *reinterpret_cast<short*>(&h);
}
DEV float us2f(unsigned short u) { return __uint_as_float((unsigned)u << 16); }
DEV unsigned short f2us(float f) {
  __hip_bfloat16 h = __float2bfloat16(f);
  return *reinterpret_cast<unsigned short*>(&h);
}
DEV float lo16(unsigned u) { return __uint_as_float(u << 16); }
DEV float hi16(unsigned u) { return __uint_as_float(u & 0xffff0000u); }

DEV float waveSum(float v) {
#pragma unroll
  for (int o = 32; o > 0; o >>= 1) v += __shfl_down(v, o, 64);
  return v;
}
DEV float waveMax(float v) {
#pragma unroll
  for (int o = 32; o > 0; o >>= 1) v = fmaxf(v, __shfl_down(v, o, 64));
  return v;
}
DEV float blockSum(float v, float* sb) {
  v = waveSum(v);
  int lane = threadIdx.x & 63, w = threadIdx.x >> 6;
  __syncthreads();
  if (lane == 0) sb[w] = v;
  __syncthreads();
  return sb[0] + sb[1] + sb[2] + sb[3];
}
DEV float blockMax(float v, float* sb) {
  v = waveMax(v);
  int lane = threadIdx.x & 63, w = threadIdx.x >> 6;
  __syncthreads();
  if (lane == 0) sb[w] = v;
  __syncthreads();
  return fmaxf(fmaxf(sb[0], sb[1]), fmaxf(sb[2], sb[3]));
}

// ---------------- runtime dtype detection ----------------
__global__ __launch_bounds__(256) void detect_k(const unsigned* __restrict__ x,
                                                int* __restrict__ flag) {
  __shared__ int sc[4];
  int t = threadIdx.x;
  int cb = 0;
  for (int i = t; i < 4096; i += 256) {
    unsigned w = x[i];
    float b0 = __uint_as_float(w << 16);
    float b1 = __uint_as_float(w & 0xffff0000u);
    if (fabsf(b0) < 64.0f && (b0 == 0.0f || fabsf(b0) > 1e-20f)) cb++;
    if (fabsf(b1) < 64.0f && (b1 == 0.0f || fabsf(b1) > 1e-20f)) cb++;
  }
#pragma unroll
  for (int o = 32; o > 0; o >>= 1) cb += __shfl_down(cb, o, 64);
  if ((t & 63) == 0) sc[t >> 6] = cb;
  __syncthreads();
  if (t == 0) flag[0] = (sc[0] + sc[1] + sc[2] + sc[3] > 7373) ? 1 : 0;  // 1 = bf16 inputs
}

__global__ void cvt_any_k(const void* __restrict__ s, float* __restrict__ d, int n,
                          const int* __restrict__ flag) {
  int i = blockIdx.x * 256 + threadIdx.x;
  if (i >= n) return;
  if (*flag)
    d[i] = toF(((const __hip_bfloat16*)s)[i]);
  else
    d[i] = ((const float*)s)[i];
}

// weight [K][N] -> bf16 transposed [N][K]
__global__ void cvtT_k(const void* __restrict__ s, __hip_bfloat16* __restrict__ d, int K, int N,
                       const int* __restrict__ flag) {
  int i = blockIdx.x * 256 + threadIdx.x;
  if (i >= N * K) return;
  int n = i / K, k = i - n * K;
  float v = (*flag) ? toF(((const __hip_bfloat16*)s)[(long)k * N + n])
                    : ((const float*)s)[(long)k * N + n];
  d[i] = f2b(v);
}

__global__ void f32tob16_k(const float* __restrict__ s, __hip_bfloat16* __restrict__ d, int n) {
  int i = blockIdx.x * 256 + threadIdx.x;
  if (i < n) d[i] = f2b(s[i]);
}

// ---------------- LN kernels ----------------

__global__ __launch_bounds__(256) void ln1_k(const void* __restrict__ xv,
                                             const float* __restrict__ g,
                                             const float* __restrict__ be,
                                             __hip_bfloat16* __restrict__ o,
                                             const int* __restrict__ flag) {
  __shared__ float sb[4];
  size_t row = blockIdx.x;
  __hip_bfloat16* po = o + row * kD;
  int t = threadIdx.x;
  float v0, v1;
  if (*flag) {
    const __hip_bfloat16* pr = (const __hip_bfloat16*)xv + row * kD;
    v0 = toF(pr[t]);
    v1 = toF(pr[t + 256]);
  } else {
    const float* pr = (const float*)xv + row * kD;
    v0 = pr[t];
    v1 = pr[t + 256];
  }
  float s = blockSum(v0 + v1, sb);
  float ss = blockSum(v0 * v0 + v1 * v1, sb);
  float mu = s * (1.0f / kD);
  float var = ss * (1.0f / kD) - mu * mu;
  float rs = rsqrtf(var + 1e-5f);
  po[t] = f2b((v0 - mu) * rs * g[t] + be[t]);
  po[t + 256] = f2b((v1 - mu) * rs * g[t + 256] + be[t + 256]);
}

__global__ __launch_bounds__(256) void ln2stats_k(const float* __restrict__ x,
                                                  float* __restrict__ st) {
  __shared__ float sb[4];
  size_t row = blockIdx.x;
  const float* pr = x + row * kD;
  int t = threadIdx.x;
  float v0 = pr[t], v1 = pr[t + 256];
  float s = blockSum(v0 + v1, sb);
  float ss = blockSum(v0 * v0 + v1 * v1, sb);
  if (t == 0) {
    float mu = s * (1.0f / kD);
    float var = ss * (1.0f / kD) - mu * mu;
    st[2 * row] = mu;
    st[2 * row + 1] = rsqrtf(var + 1e-5f);
  }
}

// ---------------- small helpers ----------------

__global__ void landmark_k(const __hip_bfloat16* __restrict__ src, float* __restrict__ dst) {
  int i = blockIdx.x * 256 + threadIdx.x;
  if (i >= kBH * kM * kDH) return;
  int dh = i & 63, m = (i >> 6) & 255, bh = i >> 14;
  const __hip_bfloat16* p = src + ((size_t)bh * kN + m * kL) * kDH + dh;
  float s = 0.f;
#pragma unroll
  for (int l = 0; l < kL; ++l) s += toF(p[l * kDH]);
  dst[i] = s * (1.0f / kL);
}

__global__ __launch_bounds__(256) void softmax_k(float* __restrict__ X, int ncols) {
  __shared__ float sb[4];
  size_t row = blockIdx.x;
  float* p = X + row * ncols;
  int t = threadIdx.x;
  float mx = -1e30f;
  for (int c = t; c < ncols; c += 256) mx = fmaxf(mx, p[c]);
  mx = blockMax(mx, sb);
  float s = 0.f;
  for (int c = t; c < ncols; c += 256) {
    float e = expf(fminf(p[c] - mx, 0.0f));
    p[c] = e;
    s += e;
  }
  s = blockSum(s, sb);
  float inv = 1.0f / s;
  for (int c = t; c < ncols; c += 256) p[c] *= inv;
}

__global__ __launch_bounds__(256) void pinv_rowcol_k(const float* __restrict__ a2,
                                                     float* __restrict__ rsum,
                                                     float* __restrict__ csum) {
  __shared__ float sb[4];
  int bh = blockIdx.x >> 8, i = blockIdx.x & 255;
  const float* base = a2 + ((size_t)bh << 16);
  int t = threadIdx.x;
  float rs = blockSum(fabsf(base[i * kM + t]), sb);
  float cs = blockSum(fabsf(base[t * kM + i]), sb);
  if (t == 0) {
    rsum[blockIdx.x] = rs;
    csum[blockIdx.x] = cs;
  }
}

__global__ __launch_bounds__(256) void pinv_gmax_k(const float* __restrict__ rsum,
                                                   const float* __restrict__ csum,
                                                   float* __restrict__ gmax) {
  __shared__ float sb[4];
  int t = threadIdx.x;
  float a = 0.f, b = 0.f;
  for (int j = t; j < kBH * kM; j += 256) {
    a = fmaxf(a, rsum[j]);
    b = fmaxf(b, csum[j]);
  }
  a = blockMax(a, sb);
  b = blockMax(b, sb);
  if (t == 0) {
    gmax[0] = a;
    gmax[1] = b;
  }
}

__global__ void pinv_init_k(const float* __restrict__ a2, const float* __restrict__ gmax,
                            __hip_bfloat16* __restrict__ z) {
  int i = blockIdx.x * 256 + threadIdx.x;
  if (i >= kBH * kM * kM) return;
  int col = i & 255, r = (i >> 8) & 255, bh = i >> 16;
  float denom = fmaxf(gmax[0] * gmax[1], 1e-30f);
  z[i] = f2b(a2[((size_t)bh << 16) + col * kM + r] / denom);
}

__global__ void conv_add_k(const __hip_bfloat16* __restrict__ v, const float* __restrict__ w,
                           __hip_bfloat16* __restrict__ ao) {
  int i = blockIdx.x * 256 + threadIdx.x;
  if (i >= kBN * kHD) return;
  int dh = i & 63, h = (i >> 6) & 7, n = (i >> 9) & (kN - 1), b = i >> 21;
  const __hip_bfloat16* vp = v + ((size_t)(b * kH + h) * kN) * kDH + dh;
  float s = 0.f;
#pragma unroll
  for (int kk = 0; kk < kCK; ++kk) {
    int nn = n + kk - kCK / 2;
    if (nn >= 0 && nn < kN) s += toF(vp[(size_t)nn * kDH]) * w[h * kCK + kk];
  }
  ao[i] = f2b(toF(ao[i]) + s);
}

// ---------------- fused streaming attention kernels (unchanged) ----------------

__global__ __launch_bounds__(256) void attn3v_k(const float* __restrict__ ql,
                                                const __hip_bfloat16* __restrict__ k,
                                                const __hip_bfloat16* __restrict__ v,
                                                float* __restrict__ w3) {
  __shared__ float qrow[4][64];
  __shared__ unsigned short p[4][4096];
  __shared__ float red[4][4][64];
  __shared__ float sb[4];
  int bh = blockIdx.x >> 6, m0 = (blockIdx.x & 63) * 4;
  int t = threadIdx.x;
  {
    int m4 = t >> 6, d = t & 63;
    qrow[m4][d] = ql[((size_t)bh * kM + m0 + m4) * kDH + d];
  }
  __syncthreads();
  const __hip_bfloat16* kp = k + (size_t)bh * kN * kDH;
  float s[4][16];
  float lmax[4] = {-1e30f, -1e30f, -1e30f, -1e30f};
  for (int c = 0; c < 16; ++c) {
    int n = c * 256 + t;
    const uint4* kr = reinterpret_cast<const uint4*>(kp + (size_t)n * kDH);
    float sm[4] = {0.f, 0.f, 0.f, 0.f};
#pragma unroll
    for (int g = 0; g < 8; ++g) {
      uint4 u = kr[g];
      float f[8] = {lo16(u.x), hi16(u.x), lo16(u.y), hi16(u.y),
                    lo16(u.z), hi16(u.z), lo16(u.w), hi16(u.w)};
#pragma unroll
      for (int e = 0; e < 8; ++e) {
        float kv = f[e];
#pragma unroll
        for (int m = 0; m < 4; ++m) sm[m] += kv * qrow[m][g * 8 + e];
      }
    }
#pragma unroll
    for (int m = 0; m < 4; ++m) {
      s[m][c] = sm[m];
      lmax[m] = fmaxf(lmax[m], sm[m]);
    }
  }
  float mx[4];
#pragma unroll
  for (int m = 0; m < 4; ++m) mx[m] = blockMax(lmax[m], sb);
  float lsum[4] = {0.f, 0.f, 0.f, 0.f};
  for (int c = 0; c < 16; ++c) {
    int n = c * 256 + t;
#pragma unroll
    for (int m = 0; m < 4; ++m) {
      float e = expf(fminf(s[m][c] - mx[m], 0.0f));
      p[m][n] = f2us(e);
      lsum[m] += e;
    }
  }
  float inv[4];
#pragma unroll
  for (int m = 0; m < 4; ++m) inv[m] = 1.0f / blockSum(lsum[m], sb);
  __syncthreads();
  int chunk = t >> 6, dh = t & 63;
  float acc[4] = {0.f, 0.f, 0.f, 0.f};
  const __hip_bfloat16* vb = v + ((size_t)bh * kN + chunk * 1024) * kDH + dh;
  for (int ni = 0; ni < 1024; ++ni) {
    float pv = toF(vb[(size_t)ni * kDH]);
    int n = chunk * 1024 + ni;
#pragma unroll
    for (int m = 0; m < 4; ++m) acc[m] += us2f(p[m][n]) * pv;
  }
#pragma unroll
  for (int m = 0; m < 4; ++m) red[chunk][m][dh] = acc[m];
  __syncthreads();
  {
    int m = t >> 6, d2 = t & 63;
    float s2 = red[0][m][d2] + red[1][m][d2] + red[2][m][d2] + red[3][m][d2];
    w3[((size_t)bh * kM + m0 + m) * kDH + d2] = s2 * inv[m];
  }
}

__global__ __launch_bounds__(256) void attn1y_k(const __hip_bfloat16* __restrict__ q,
                                                const float* __restrict__ kl,
                                                const float* __restrict__ y,
                                                __hip_bfloat16* __restrict__ ao) {
  __shared__ float qt[64][64];
  __shared__ unsigned short p[64][256];
  __shared__ float m4[64][4];
  __shared__ float rinv[64];
  int bh = blockIdx.x >> 6, n0 = (blockIdx.x & 63) * 64;
  int b = bh >> 3, h = bh & 7;
  int t = threadIdx.x;
  const __hip_bfloat16* qp = q + ((size_t)bh * kN + n0) * kDH;
#pragma unroll
  for (int i = 0; i < 16; ++i) {
    int idx = t + i * 256;
    int r = idx >> 6, d = idx & 63;
    qt[r][d] = toF(qp[(size_t)r * kDH + d]);
  }
  __syncthreads();
  float klr[64];
  const float* klp = kl + ((size_t)bh * kM + t) * kDH;
#pragma unroll
  for (int d = 0; d < 64; ++d) klr[d] = klp[d];
  for (int r = 0; r < 64; ++r) {
    float s = 0.f;
#pragma unroll
    for (int d = 0; d < 64; ++d) s += qt[r][d] * klr[d];
    p[r][t] = f2us(s);
  }
  __syncthreads();
  int r = t >> 2, seg = t & 3;
  float mx = -1e30f;
  for (int j = seg * 64; j < seg * 64 + 64; ++j) mx = fmaxf(mx, us2f(p[r][j]));
  m4[r][seg] = mx;
  __syncthreads();
  float rm = fmaxf(fmaxf(m4[r][0], m4[r][1]), fmaxf(m4[r][2], m4[r][3]));
  __syncthreads();
  float sum = 0.f;
  for (int j = seg * 64; j < seg * 64 + 64; ++j) {
    float e = expf(fminf(us2f(p[r][j]) - rm, 0.0f));
    p[r][j] = f2us(e);
    sum += e;
  }
  m4[r][seg] = sum;
  __syncthreads();
  if (seg == 0) rinv[r] = 1.0f / (m4[r][0] + m4[r][1] + m4[r][2] + m4[r][3]);
  __syncthreads();
  int dh = t & 63, rg = t >> 6;
  const float* yp = y + (size_t)bh * kM * kDH + dh;
  for (int rr = rg * 16; rr < rg * 16 + 16; ++rr) {
    float acc = 0.f;
    for (int j = 0; j < 256; ++j) acc += us2f(p[rr][j]) * yp[(size_t)j * kDH];
    acc *= rinv[rr];
    ao[((size_t)(b * kN + n0 + rr)) * kHD + h * kDH + dh] = f2b(acc);
  }
}

// ---------------- epilogue / arg pack ----------------
constexpr int EPI_F32 = 0, EPI_QKV = 1, EPI_BIAS_F32 = 2, EPI_GELU_BF16 = 3, EPI_RES_OUT = 4,
              EPI_BF16 = 5;

struct EpiArgs {
  const float* bias;
  const float* res;
  __hip_bfloat16* oq;
  __hip_bfloat16* ok;
  __hip_bfloat16* ov;
  __hip_bfloat16* obf;
  const float* stats;
  const float* g;
  const float* be;
  void* ovoid;
  const int* flag;
  float eyeC;
  float eyeS;
};

// ---------------- MFMA bf16 GEMM: 128x128 tile, BK=32, 4 waves ----------------
// A [M][K] (bf16, or f32 with fused LN when LNA). B bf16: TRB -> [N][K]; else [K][N]
// (gather staging, optional fused (eyeC*I - B)*eyeS transform). f32 accumulate.
template <int EPI, bool TRB, bool BEYE, bool LNA, class TAT>
__global__ __launch_bounds__(256) void mgemm_k(const TAT* __restrict__ A, int lda, long sA,
                                               const __hip_bfloat16* __restrict__ B, int ldb,
                                               long sB, float* __restrict__ C, int ldc, long sC,
                                               int K, EpiArgs ep) {
  __shared__ short As[128 * 40];
  __shared__ short Bs[128 * 40];
  A += (long)blockIdx.z * sA;
  B += (long)blockIdx.z * sB;
  const long cbase = (long)blockIdx.z * sC;
  const int row0 = blockIdx.x * 128, col0 = blockIdx.y * 128;
  const int t = threadIdx.x;
  const int lane = t & 63, wave = t >> 6;
  const int wr = (wave >> 1) * 64, wc = (wave & 1) * 64;
  const int l15 = lane & 15, quad = lane >> 4;
  f32x4 acc[4][4] = {};
  for (int k0 = 0; k0 < K; k0 += 32) {
    // ---- stage A (128x32) ----
    {
      const int kc = (t & 3) * 8;
#pragma unroll
      for (int p = 0; p < 2; ++p) {
        const int m = p * 64 + (t >> 2);
        const long r = row0 + m;
        if constexpr (LNA) {
          const float* ap = (const float*)A + r * lda + k0 + kc;
          float mu = ep.stats[2 * r], rs = ep.stats[2 * r + 1];
          short8 vv;
#pragma unroll
          for (int e = 0; e < 8; ++e)
            vv[e] = f2s((ap[e] - mu) * rs * ep.g[k0 + kc + e] + ep.be[k0 + kc + e]);
          *(short8*)(&As[m * 40 + kc]) = vv;
        } else {
          uint4 u = *(const uint4*)((const __hip_bfloat16*)A + r * lda + k0 + kc);
          *(uint4*)(&As[m * 40 + kc]) = u;
        }
      }
    }
    // ---- stage B (as [n][k]) ----
    if (TRB) {
      const int kc = (t & 3) * 8;
#pragma unroll
      for (int p = 0; p < 2; ++p) {
        const int n = p * 64 + (t >> 2);
        uint4 u = *(const uint4*)(B + (long)(col0 + n) * ldb + k0 + kc);
        *(uint4*)(&Bs[n * 40 + kc]) = u;
      }
    } else {
      const int k8 = (t & 3) * 8;
#pragma unroll
      for (int p = 0; p < 2; ++p) {
        const int n = p * 64 + (t >> 2);
        short8 vv;
#pragma unroll
        for (int e = 0; e < 8; ++e) {
          float v = toF(B[(long)(k0 + k8 + e) * ldb + col0 + n]);
          if constexpr (BEYE) v = (((k0 + k8 + e) == (col0 + n)) ? ep.eyeC : 0.0f) - v;
          vv[e] = f2s(BEYE ? v * ep.eyeS : v);
        }
        *(short8*)(&Bs[n * 40 + k8]) = vv;
      }
    }
    __syncthreads();
    short8 af[4], bf[4];
#pragma unroll
    for (int i = 0; i < 4; ++i)
      af[i] = *(const short8*)(&As[(wr + i * 16 + l15) * 40 + quad * 8]);
#pragma unroll
    for (int j = 0; j < 4; ++j)
      bf[j] = *(const short8*)(&Bs[(wc + j * 16 + l15) * 40 + quad * 8]);
#pragma unroll
    for (int i = 0; i < 4; ++i)
#pragma unroll
      for (int j = 0; j < 4; ++j)
        acc[i][j] = __builtin_amdgcn_mfma_f32_16x16x32_bf16(af[i], bf[j], acc[i][j], 0, 0, 0);
    __syncthreads();
  }
  // ---- epilogue (C/D: col=lane&15, row=quad*4+reg) ----
#pragma unroll
  for (int i = 0; i < 4; ++i) {
#pragma unroll
    for (int j = 0; j < 4; ++j) {
#pragma unroll
      for (int rg = 0; rg < 4; ++rg) {
        int r = row0 + wr + i * 16 + quad * 4 + rg;
        int c = col0 + wc + j * 16 + l15;
        float v = acc[i][j][rg];
        if (EPI == EPI_BF16) {
          ep.obf[cbase + (long)r * ldc + c] = f2b(v);
        } else if (EPI == EPI_QKV) {
          int three = c >> 9, h = (c >> 6) & 7, dh = c & 63;
          int b = r >> 12, n = r & (kN - 1);
          long dst = ((long)(b * kH + h) * kN + n) * kDH + dh;
          if (three == 0)
            ep.oq[dst] = f2b(v * 0.125f);
          else if (three == 1)
            ep.ok[dst] = f2b(v);
          else
            ep.ov[dst] = f2b(v);
        } else if (EPI == EPI_BIAS_F32) {
          C[cbase + (long)r * ldc + c] = v + ep.bias[c];
        } else if (EPI == EPI_GELU_BF16) {
          v += ep.bias[c];
          ep.obf[cbase + (long)r * ldc + c] =
              f2b(0.5f * v * (1.0f + erff(v * 0.70710678118654752f)));
        } else if (EPI == EPI_RES_OUT) {
          long idx = cbase + (long)r * ldc + c;
          float v2 = v + ep.bias[c] + ep.res[idx];
          if (!(v2 == v2)) v2 = 0.0f;
          if (*ep.flag)
            ((__hip_bfloat16*)ep.ovoid)[idx] = f2b(v2);
          else
            ((float*)ep.ovoid)[idx] = v2;
        }
      }
    }
  }
}

// ---------------- fp32 vector GEMM (for small/odd shapes: sim2, y) ----------------
template <int EPI, bool TRB, class TAT, class TBT>
__global__ __launch_bounds__(256) void gemm_k(const TAT* __restrict__ A, int lda, long sA,
                                              const TBT* __restrict__ B, int ldb, long sB,
                                              float* __restrict__ C, int ldc, long sC, int K,
                                              EpiArgs ep) {
  __shared__ float As[16][68];
  __shared__ float Bs[16][68];
  A += (long)blockIdx.z * sA;
  B += (long)blockIdx.z * sB;
  const long cbase = (long)blockIdx.z * sC;
  const int row0 = blockIdx.x * 64, col0 = blockIdx.y * 64;
  const int t = threadIdx.x;
  const int ty = t >> 4, tx = t & 15;
  float acc[4][4] = {{0.f, 0.f, 0.f, 0.f}, {0.f, 0.f, 0.f, 0.f},
                     {0.f, 0.f, 0.f, 0.f}, {0.f, 0.f, 0.f, 0.f}};
  const int ka = t & 15, ra = t >> 4;
  for (int k0 = 0; k0 < K; k0 += 16) {
#pragma unroll
    for (int j = 0; j < 4; ++j)
      As[ka][ra + 16 * j] = toF(A[(long)(row0 + ra + 16 * j) * lda + (k0 + ka)]);
    if (TRB) {
#pragma unroll
      for (int j = 0; j < 4; ++j)
        Bs[ka][ra + 16 * j] = toF(B[(long)(col0 + ra + 16 * j) * ldb + (k0 + ka)]);
    } else {
      const int jb = t & 63, kb = t >> 6;
#pragma unroll
      for (int j = 0; j < 4; ++j)
        Bs[kb + 4 * j][jb] = toF(B[(long)(k0 + kb + 4 * j) * ldb + (col0 + jb)]);
    }
    __syncthreads();
#pragma unroll
    for (int kk = 0; kk < 16; ++kk) {
      float av[4], bv[4];
#pragma unroll
      for (int i = 0; i < 4; ++i) av[i] = As[kk][ty * 4 + i];
#pragma unroll
      for (int j = 0; j < 4; ++j) bv[j] = Bs[kk][tx * 4 + j];
#pragma unroll
      for (int i = 0; i < 4; ++i)
#pragma unroll
        for (int j = 0; j < 4; ++j) acc[i][j] += av[i] * bv[j];
    }
    __syncthreads();
  }
#pragma unroll
  for (int i = 0; i < 4; ++i) {
    int r = row0 + ty * 4 + i;
#pragma unroll
    for (int j = 0; j < 4; ++j) {
      int c = col0 + tx * 4 + j;
      C[cbase + (long)r * ldc + c] = acc[i][j];
    }
  }
}

}  // namespace

extern "C" void kernel_launch(void* const* d_in, const int* in_sizes, int n_in, void* d_out,
                              int out_size, void* d_ws, size_t ws_size, hipStream_t stream) {
  (void)in_sizes; (void)n_in; (void)out_size;

  char* base = (char*)d_ws;
  size_t off = 0;
  auto alloc = [&](size_t bytes) {
    char* p = base + off;
    off = (off + bytes + 255) & ~(size_t)255;
    return p;
  };
  // a2 + 4 pinv slots (slots sized for f32 to keep hbuf contiguity; used as bf16)
  float* a2 = (float*)alloc((size_t)kBH * kM * kM * 4);  // 16.78 MB
  __hip_bfloat16* zs0 = (__hip_bfloat16*)alloc((size_t)kBH * kM * kM * 4);
  __hip_bfloat16* zs1 = (__hip_bfloat16*)alloc((size_t)kBH * kM * kM * 4);
  __hip_bfloat16* zs2 = (__hip_bfloat16*)alloc((size_t)kBH * kM * kM * 4);
  __hip_bfloat16* zs3 = (__hip_bfloat16*)alloc((size_t)kBH * kM * kM * 4);
  __hip_bfloat16* a2b = (__hip_bfloat16*)alloc((size_t)kBH * kM * kM * 2);  // 8.39 MB
  // bf16 qkv + attn-out region (hosts MLP hidden late: 134.2 MB contiguous)
  __hip_bfloat16* q = (__hip_bfloat16*)alloc((size_t)kBH * kN * kDH * 2);
  __hip_bfloat16* kk = (__hip_bfloat16*)alloc((size_t)kBH * kN * kDH * 2);
  __hip_bfloat16* vv = (__hip_bfloat16*)alloc((size_t)kBH * kN * kDH * 2);
  __hip_bfloat16* ao = (__hip_bfloat16*)alloc((size_t)kBN * kHD * 2);
  float* ql = (float*)alloc((size_t)kBH * kM * kDH * 4);
  float* kl = (float*)alloc((size_t)kBH * kM * kDH * 4);
  float* w3 = (float*)alloc((size_t)kBH * kM * kDH * 4);
  float* y = (float*)alloc((size_t)kBH * kM * kDH * 4);
  float* st2 = (float*)alloc((size_t)kBN * 2 * 4);
  float* rsum = (float*)alloc((size_t)kBH * kM * 4);
  float* csum = (float*)alloc((size_t)kBH * kM * 4);
  float* gmax = (float*)alloc(256);
  int* dflag = (int*)alloc(256);
  // transposed bf16 weights
  __hip_bfloat16* WqkvT = (__hip_bfloat16*)alloc((size_t)kQKVC * kD * 2);
  __hip_bfloat16* WoutT = (__hip_bfloat16*)alloc((size_t)kD * kHD * 2);
  __hip_bfloat16* W1T = (__hip_bfloat16*)alloc((size_t)kD4 * kD * 2);
  __hip_bfloat16* W2T = (__hip_bfloat16*)alloc((size_t)kD * kD4 * 2);
  float* bout_f = (float*)alloc(kD * 4);
  float* b1_f = (float*)alloc(kD4 * 4);
  float* b2_f = (float*)alloc(kD * 4);
  float* convw_f = (float*)alloc(kH * kCK * 4);
  float* g1_f = (float*)alloc(kD * 4);
  float* be1_f = (float*)alloc(kD * 4);
  float* g2_f = (float*)alloc(kD * 4);
  float* be2_f = (float*)alloc(kD * 4);
  // lifetime-disjoint aliases
  __hip_bfloat16* hln = (__hip_bfloat16*)a2;  // LN1 out, spans a2+zs0+half zs1, dead pre-sim2
  float* hbuf = a2;                           // Wout out f32 67.1MB, spans a2+zs0..zs2
  __hip_bfloat16* hidden = q;                 // MLP hidden bf16 134.2MB, spans q..ao

  if (off > ws_size) return;  // deterministic guard

  detect_k<<<1, 256, 0, stream>>>((const unsigned*)d_in[0], dflag);

  auto cvt = [&](const void* src, float* dst, int n) {
    cvt_any_k<<<(n + 255) / 256, 256, 0, stream>>>(src, dst, n, dflag);
  };
  cvtT_k<<<(kD * kQKVC + 255) / 256, 256, 0, stream>>>(d_in[1], WqkvT, kD, kQKVC, dflag);
  cvtT_k<<<(kHD * kD + 255) / 256, 256, 0, stream>>>(d_in[2], WoutT, kHD, kD, dflag);
  cvtT_k<<<(kD * kD4 + 255) / 256, 256, 0, stream>>>(d_in[9], W1T, kD, kD4, dflag);
  cvtT_k<<<(kD4 * kD + 255) / 256, 256, 0, stream>>>(d_in[11], W2T, kD4, kD, dflag);
  cvt(d_in[3], bout_f, kD);
  cvt(d_in[4], convw_f, kH * kCK);
  cvt(d_in[5], g1_f, kD);
  cvt(d_in[6], be1_f, kD);
  cvt(d_in[7], g2_f, kD);
  cvt(d_in[8], be2_f, kD);
  cvt(d_in[10], b1_f, kD4);
  cvt(d_in[12], b2_f, kD);

  EpiArgs e0 = {};

  // LN1 -> hln (bf16)
  ln1_k<<<kBN, 256, 0, stream>>>(d_in[0], g1_f, be1_f, hln, dflag);

  // QKV: hln @ WqkvT^T (MFMA, scatter epilogue)
  EpiArgs eq = {};
  eq.oq = q; eq.ok = kk; eq.ov = vv;
  mgemm_k<EPI_QKV, true, false, false, __hip_bfloat16>
      <<<dim3(kBN / 128, kQKVC / 128, 1), 256, 0, stream>>>(hln, kD, 0, WqkvT, kD, 0, nullptr, 0,
                                                            0, kD, eq);

  landmark_k<<<(kBH * kM * kDH + 255) / 256, 256, 0, stream>>>(q, ql);
  landmark_k<<<(kBH * kM * kDH + 255) / 256, 256, 0, stream>>>(kk, kl);

  const long sQL = (long)kM * kDH, sA2 = (long)kM * kM;

  // sim2 = q_l @ k_l^T (f32) ; softmax
  gemm_k<EPI_F32, true, float, float><<<dim3(kM / 64, kM / 64, kBH), 256, 0, stream>>>(
      ql, kDH, sQL, kl, kDH, sQL, a2, kM, sA2, kDH, e0);
  softmax_k<<<kBH * kM, 256, 0, stream>>>(a2, kM);

  // pinv setup
  f32tob16_k<<<(kBH * kM * kM + 255) / 256, 256, 0, stream>>>(a2, a2b, kBH * kM * kM);
  pinv_rowcol_k<<<kBH * kM, 256, 0, stream>>>(a2, rsum, csum);
  pinv_gmax_k<<<1, 256, 0, stream>>>(rsum, csum, gmax);
  pinv_init_k<<<(kBH * kM * kM + 255) / 256, 256, 0, stream>>>(a2, gmax, zs0);

  // Newton-Schulz: 4 MFMA GEMMs/iter, eye-ops fused into B staging
  __hip_bfloat16* bufs[4] = {zs0, zs1, zs2, zs3};
  int zi = 0;
  dim3 gP(kM / 128, kM / 128, kBH);
  for (int it = 0; it < 6; ++it) {
    int o0 = (zi + 1) & 3, o1 = (zi + 2) & 3, o2 = (zi + 3) & 3;
    __hip_bfloat16* Z = bufs[zi];
    __hip_bfloat16* T1 = bufs[o0];
    __hip_bfloat16* T3 = bufs[o1];
    __hip_bfloat16* P3 = bufs[o2];
    EpiArgs ep1 = {}; ep1.obf = T1;
    mgemm_k<EPI_BF16, false, false, false, __hip_bfloat16><<<gP, 256, 0, stream>>>(
        a2b, kM, sA2, Z, kM, sA2, nullptr, kM, sA2, kM, ep1);
    EpiArgs ep2 = {}; ep2.obf = T3; ep2.eyeC = 7.0f; ep2.eyeS = 1.0f;
    mgemm_k<EPI_BF16, false, true, false, __hip_bfloat16><<<gP, 256, 0, stream>>>(
        T1, kM, sA2, T1, kM, sA2, nullptr, kM, sA2, kM, ep2);
    EpiArgs ep3 = {}; ep3.obf = P3; ep3.eyeC = 15.0f; ep3.eyeS = 1.0f;
    mgemm_k<EPI_BF16, false, true, false, __hip_bfloat16><<<gP, 256, 0, stream>>>(
        T1, kM, sA2, T3, kM, sA2, nullptr, kM, sA2, kM, ep3);
    EpiArgs ep4 = {}; ep4.obf = T3; ep4.eyeC = 13.0f; ep4.eyeS = 0.25f;
    mgemm_k<EPI_BF16, false, true, false, __hip_bfloat16><<<gP, 256, 0, stream>>>(
        Z, kM, sA2, P3, kM, sA2, nullptr, kM, sA2, kM, ep4);
    zi = o1;
  }
  __hip_bfloat16* zfin = bufs[zi];

  // w3 = softmax(q_l @ k^T) @ v  (fused streaming)
  attn3v_k<<<kBH * (kM / 4), 256, 0, stream>>>(ql, kk, vv, w3);

  // y = z @ w3 (f32 vector gemm; N=64)
  gemm_k<EPI_F32, false, __hip_bfloat16, float><<<dim3(kM / 64, 1, kBH), 256, 0, stream>>>(
      zfin, kM, sA2, w3, kDH, sQL, y, kDH, sQL, kM, e0);

  // ao = softmax(q @ k_l^T) @ y  (fused streaming, merged layout)
  attn1y_k<<<kBH * (kN / 64), 256, 0, stream>>>(q, kl, y, ao);

  // + depthwise conv residual
  conv_add_k<<<(kBN * kHD + 255) / 256, 256, 0, stream>>>(vv, convw_f, ao);

  // hbuf = ao @ WoutT^T + bout (MFMA, f32 out)
  EpiArgs ew = {}; ew.bias = bout_f;
  mgemm_k<EPI_BIAS_F32, true, false, false, __hip_bfloat16>
      <<<dim3(kBN / 128, kD / 128, 1), 256, 0, stream>>>(ao, kHD, 0, WoutT, kHD, 0, hbuf, kD, 0,
                                                         kHD, ew);

  // LN2 stats; MLP1 (LN fused in A-staging, +bias+GELU -> bf16 hidden)
  ln2stats_k<<<kBN, 256, 0, stream>>>(hbuf, st2);
  EpiArgs e1 = {}; e1.bias = b1_f; e1.stats = st2; e1.g = g2_f; e1.be = be2_f; e1.obf = hidden;
  mgemm_k<EPI_GELU_BF16, true, false, true, float>
      <<<dim3(kBN / 128, kD4 / 128, 1), 256, 0, stream>>>(hbuf, kD, 0, W1T, kD, 0, nullptr, kD4,
                                                          0, kD, e1);

  // MLP2 (+bias+residual -> flag-typed out)
  EpiArgs e2 = {}; e2.bias = b2_f; e2.res = hbuf; e2.ovoid = d_out; e2.flag = dflag;
  mgemm_k<EPI_RES_OUT, true, false, false, __hip_bfloat16>
      <<<dim3(kBN / 128, kD / 128, 1), 256, 0, stream>>>(hidden, kD4, 0, W2T, kD4, 0, nullptr,
                                                         kD, 0, kD4, e2);
}